// Round 4
// baseline (661.082 us; speedup 1.0000x reference)
//
#include <hip/hip_runtime.h>
#include <cstdint>

// SparseMLP: out = relu(relu(x@W1^T+b1)@W2^T+b2)@W3^T+b3
// M = N = K = 4096 per layer. fp32 in/out; fp16 MFMA internally.
//
// R8 vs R7 (589us; GEMM 121.6us == R6 == R4 -> schedule axis falsified):
// keep R7's 4-phase counted-lgkm skeleton, change the DATA LAYOUT:
// fragment-linear LDS (m173/s09 "pre-swizzle global, keep LDS linear").
//  - LDS region (16KB) = [frag 0..7][16B x 64 lanes]: each MFMA fragment
//    (16 rows x 32 k) is one contiguous 1KB block; block index b = fi*2+ks.
//  - ds_read = base + lane*16 + imm (linear, conflict-free, 1 base reg);
//    replaces scattered row*128 + XOR-slot*16 reads (bank-balanced but
//    m198-level slow: we sat at m198's 1167 TF / 46% MfmaUtil exactly).
//  - glds16 global source pre-arranged: wave w issue j writes block j*8+w;
//    lane l sources (row = l&15, koct = l>>4) -> 64B-contiguous per row,
//    parity-partner wave fetches the adjacent 64B (full-line use).
//  - wave tiling now contiguous: wave wm owns rows wm*128..+128 (region
//    Ah[wm] whole), acc[mi] <-> row wm*128+mi*16; epilogue re-derived.
//  - lgkm counts order-robust: P0 lgkm(0) (12 in-phase reads), P1 lgkm(8)
//    (no-op), P2 lgkm(4) (=P1's 8 landed), P3 lgkm(0) (=P2's 4 landed) --
//    inter-phase order fixed by memory-clobber barriers, intra-phase free.
// STAGE slots/vmcnt ledger identical to R7 (audited, passed).

#define MATN 4096
#define NT (MATN / 64)  // 64 K-tiles

typedef _Float16 half8 __attribute__((ext_vector_type(8)));
typedef float f32x4 __attribute__((ext_vector_type(4)));

// async global->LDS, 16B/lane. LDS dest = wave-uniform base + lane*16.
__device__ __forceinline__ void glds16(const void* g, void* l) {
    __builtin_amdgcn_global_load_lds(
        (const __attribute__((address_space(1))) char*)(uintptr_t)g,
        (__attribute__((address_space(3))) char*)(uintptr_t)l,
        16, 0, 0);
}

__device__ __forceinline__ void cvt_body(const float* __restrict__ in,
                                         _Float16* __restrict__ out, int n8) {
    for (int g = blockIdx.x * 256 + threadIdx.x; g < n8; g += gridDim.x * 256) {
        size_t i = (size_t)g * 8;
        float4 a = *(const float4*)(in + i);
        float4 b = *(const float4*)(in + i + 4);
        half8 o;
        o[0] = (_Float16)a.x; o[1] = (_Float16)a.y;
        o[2] = (_Float16)a.z; o[3] = (_Float16)a.w;
        o[4] = (_Float16)b.x; o[5] = (_Float16)b.y;
        o[6] = (_Float16)b.z; o[7] = (_Float16)b.w;
        *(half8*)(out + i) = o;
    }
}

__global__ __launch_bounds__(256)
void cvt_f16(const float* __restrict__ in, _Float16* __restrict__ out, int n8) {
    cvt_body(in, out, n8);
}

__global__ __launch_bounds__(256)
void cvt_f16_2(const float* __restrict__ i0, _Float16* __restrict__ o0,
               const float* __restrict__ i1, _Float16* __restrict__ o1, int n8) {
    cvt_body(blockIdx.y ? i1 : i0, blockIdx.y ? o1 : o0, n8);
}

__global__ __launch_bounds__(256)
void cvt_f16_4(const float* __restrict__ i0, _Float16* __restrict__ o0,
               const float* __restrict__ i1, _Float16* __restrict__ o1,
               const float* __restrict__ i2, _Float16* __restrict__ o2,
               const float* __restrict__ i3, _Float16* __restrict__ o3, int n8) {
    const float* in;
    _Float16* out;
    switch (blockIdx.y) {
        case 0: in = i0; out = o0; break;
        case 1: in = i1; out = o1; break;
        case 2: in = i2; out = o2; break;
        default: in = i3; out = o3; break;
    }
    cvt_body(in, out, n8);
}

// C[m][n] = sum_k A[m][k]*B[n][k] + bias[n] (optional ReLU).
// A,B: [4096][4096] f16 row-major (K-contig). 256x256 tile, BK=64.
#define MFMA_(d, x, y) d = __builtin_amdgcn_mfma_f32_16x16x32_f16(x, y, d, 0, 0, 0)

template <bool RELU, typename OutT>
__global__ __launch_bounds__(512, 2)
void gemm_bt(const _Float16* __restrict__ A, const _Float16* __restrict__ B,
             const float* __restrict__ bias, OutT* __restrict__ C) {
    // [buf][region][16 blocks x 1KB]; region: 0=Ah0 1=Bh0 2=Bh1 3=Ah1. 128 KB.
    // Block b = frag_i*2 + ks holds fragment (rows frag_i*16..+16 of the
    // region's 128, k-slice ks*32..+32): lane l = (row l&15, k-oct l>>4).
    __shared__ _Float16 lds[2][4][128 * 64];

    const int tid  = threadIdx.x;
    const int lane = tid & 63;
    const int w    = tid >> 6;   // 8 waves
    const int wm   = w >> 2;     // 0..1  (rows wm*128..+128)
    const int wn   = w & 3;      // 0..3  (cols wn*64..+64)
    const int l16  = lane & 15;
    const int kq   = lane >> 4;  // 0..3

    // bijective XCD swizzle: 256 blocks, 256 % 8 == 0
    const int bid   = blockIdx.y * 16 + blockIdx.x;
    const int sbid  = (bid & 7) * 32 + (bid >> 3);
    const int tileM = (sbid >> 4) * 256;
    const int tileN = (sbid & 15) * 256;

    char* const ldsb = (char*)lds;

    // staging (fragment-linear): wave w issue j -> block j*8+w of the region
    // = fragment fi = j*4 + (w>>1), ks = w&1. Lane l sources global
    // (row = fi*16 + (l&15), col = T*64 + ks*32 + (l>>4)*8).
    const int rowStage = ((tid >> 7) & 3) * 16 + l16;  // (w>>1)*16 + l16
    const int colStage = (w & 1) * 32 + kq * 8;        // elems
    const _Float16* const aS = A + (size_t)(tileM + rowStage) * MATN + colStage;
    const _Float16* const bS = B + (size_t)(tileN + rowStage) * MATN + colStage;

#define STAGE_(Tt, reg, half, src)                                             \
    do {                                                                       \
        if ((Tt) < NT) {                                                       \
            const _Float16* g_ =                                               \
                (src) + (size_t)((half) * 128) * MATN + (Tt) * 64;             \
            char* l_ = ldsb + (((Tt) & 1) * 4 + (reg)) * 16384 + w * 1024;     \
            glds16(g_, l_);                                                    \
            glds16(g_ + (size_t)64 * MATN, l_ + 8192);                         \
        }                                                                      \
    } while (0)
#define STAGE_A(Tt, mh) STAGE_(Tt, (mh) * 3, mh, aS)
#define STAGE_B(Tt, nh) STAGE_(Tt, 1 + (nh), nh, bS)

    half8 aP[4], aQ[4], bP[4], bQ[4];
    f32x4 acc[8][4] = {};

    // prologue: tile0 all 4 regions + Bh1_1 = 10 loads; vmcnt(2) retires
    // tile0's 8 -> in-flight = Bh1_1 (2 loads, issued last).
    STAGE_A(0, 0);
    STAGE_B(0, 0);
    STAGE_B(0, 1);
    STAGE_A(0, 1);
    STAGE_B(1, 1);
    asm volatile("s_waitcnt vmcnt(2)" ::: "memory");
    __builtin_amdgcn_s_barrier();

#pragma unroll 2
    for (int T = 0; T < NT; ++T) {
        // per-wave linear read bases (lane*16: contiguous 1KB per frag)
        const char* Ard = ldsb + (T & 1) * 65536 + wm * 3 * 16384 + lane * 16;
        const char* Brd = ldsb + (T & 1) * 65536 + (1 + (wn >> 1)) * 16384 +
                          (wn & 1) * 8192 + lane * 16;

        // ---- P0: (h0,k0). reads aP<-A(h0,k0), bP<-B(*,k0), aQ<-A(h1,k0) ----
#pragma unroll
        for (int mi = 0; mi < 4; ++mi)
            aP[mi] = *(const half8*)(Ard + mi * 2048);
#pragma unroll
        for (int ni = 0; ni < 4; ++ni)
            bP[ni] = *(const half8*)(Brd + ni * 2048);
#pragma unroll
        for (int mi = 0; mi < 4; ++mi)
            aQ[mi] = *(const half8*)(Ard + 8192 + mi * 2048);
        STAGE_A(T + 1, 0);  // Ah0_{T+1}
        __builtin_amdgcn_s_barrier();
        asm volatile("s_waitcnt lgkmcnt(0)" ::: "memory");
        __builtin_amdgcn_sched_barrier(0);
        __builtin_amdgcn_s_setprio(1);
#pragma unroll
        for (int mi = 0; mi < 4; ++mi)
#pragma unroll
            for (int ni = 0; ni < 4; ++ni)
                MFMA_(acc[mi][ni], aP[mi], bP[ni]);
        __builtin_amdgcn_s_setprio(0);
        __builtin_amdgcn_s_barrier();

        // ---- P1: (h1,k0) uses aQ,bP. reads aP<-A(h1,k1), bQ<-B(*,k1) ----
#pragma unroll
        for (int mi = 0; mi < 4; ++mi)
            aP[mi] = *(const half8*)(Ard + 8192 + mi * 2048 + 1024);
#pragma unroll
        for (int ni = 0; ni < 4; ++ni)
            bQ[ni] = *(const half8*)(Brd + ni * 2048 + 1024);
        STAGE_A(T + 1, 1);  // Ah1_{T+1}
        __builtin_amdgcn_s_barrier();
        asm volatile("s_waitcnt lgkmcnt(8)" ::: "memory");  // no-op guard
        __builtin_amdgcn_sched_barrier(0);
        __builtin_amdgcn_s_setprio(1);
#pragma unroll
        for (int mi = 0; mi < 4; ++mi)
#pragma unroll
            for (int ni = 0; ni < 4; ++ni)
                MFMA_(acc[4 + mi][ni], aQ[mi], bP[ni]);
        __builtin_amdgcn_s_setprio(0);
        __builtin_amdgcn_s_barrier();

        // ---- P2: (h1,k1) uses aP,bQ. reads aQ<-A(h0,k1) ----
#pragma unroll
        for (int mi = 0; mi < 4; ++mi)
            aQ[mi] = *(const half8*)(Ard + mi * 2048 + 1024);
        STAGE_B(T + 1, 0);  // Bh0_{T+1}
        __builtin_amdgcn_s_barrier();
        asm volatile("s_waitcnt lgkmcnt(4)" ::: "memory");  // P1's 8 landed
        __builtin_amdgcn_sched_barrier(0);
        __builtin_amdgcn_s_setprio(1);
#pragma unroll
        for (int mi = 0; mi < 4; ++mi)
#pragma unroll
            for (int ni = 0; ni < 4; ++ni)
                MFMA_(acc[4 + mi][ni], aP[mi], bQ[ni]);
        __builtin_amdgcn_s_setprio(0);
        __builtin_amdgcn_s_barrier();

        // ---- P3: (h0,k1) uses aQ,bQ. no reads ----
        STAGE_B(T + 2, 1);  // Bh1_{T+2} (phys Bh1_T, read-done @P1)
        __builtin_amdgcn_s_barrier();
        asm volatile("s_waitcnt lgkmcnt(0)" ::: "memory");  // P2's 4 landed
        __builtin_amdgcn_sched_barrier(0);
        __builtin_amdgcn_s_setprio(1);
#pragma unroll
        for (int mi = 0; mi < 4; ++mi)
#pragma unroll
            for (int ni = 0; ni < 4; ++ni)
                MFMA_(acc[mi][ni], aQ[mi], bQ[ni]);
        __builtin_amdgcn_s_setprio(0);
        // retire T+1's 4 regions (outstanding 10 -> keep newest 2 = Bh1_{T+2});
        // tail: guards shrink issue, so drain fully.
        if (T < NT - 2)
            asm volatile("s_waitcnt vmcnt(2)" ::: "memory");
        else
            asm volatile("s_waitcnt vmcnt(0)" ::: "memory");
        __builtin_amdgcn_s_barrier();
    }
#undef STAGE_A
#undef STAGE_B
#undef STAGE_

    // epilogue: C/D layout col = lane&15, row = (lane>>4)*4 + reg (m89).
    // acc[mi][ni] <-> rows tileM + wm*128 + mi*16, cols tileN + wn*64 + ni*16.
#pragma unroll
    for (int ni = 0; ni < 4; ++ni) {
        const int gn = tileN + wn * 64 + ni * 16 + l16;
        const float bv = bias[gn];
#pragma unroll
        for (int mi = 0; mi < 8; ++mi) {
            const int gm = tileM + wm * 128 + mi * 16 + kq * 4;
#pragma unroll
            for (int r = 0; r < 4; ++r) {
                float v = acc[mi][ni][r] + bv;
                if (RELU) v = v > 0.f ? v : 0.f;
                C[(size_t)(gm + r) * MATN + gn] = (OutT)v;
            }
        }
    }
}

extern "C" void kernel_launch(void* const* d_in, const int* in_sizes, int n_in,
                              void* d_out, int out_size, void* d_ws, size_t ws_size,
                              hipStream_t stream) {
    const float* x  = (const float*)d_in[0];
    const float* W1 = (const float*)d_in[1];
    const float* b1 = (const float*)d_in[2];
    const float* W2 = (const float*)d_in[3];
    const float* b2 = (const float*)d_in[4];
    const float* W3 = (const float*)d_in[5];
    const float* b3 = (const float*)d_in[6];
    float* out = (float*)d_out;

    const size_t MAT = (size_t)MATN * MATN;
    const size_t HB  = MAT * 2;  // bytes per f16 matrix
    const int n8 = (int)(MAT / 8);
    dim3 ggrid(MATN / 256, MATN / 256);  // 16x16

    if (ws_size >= HB * 5) {
        // roomy path: all converts in one launch
        _Float16* xb = (_Float16*)d_ws;
        _Float16* w1 = (_Float16*)((char*)d_ws + HB);
        _Float16* w2 = (_Float16*)((char*)d_ws + HB * 2);
        _Float16* w3 = (_Float16*)((char*)d_ws + HB * 3);
        _Float16* h1 = (_Float16*)((char*)d_ws + HB * 4);
        _Float16* h2 = xb;  // xb dead after layer 1

        cvt_f16_4<<<dim3(2048, 4), 256, 0, stream>>>(x, xb, W1, w1, W2, w2,
                                                     W3, w3, n8);
        gemm_bt<true, _Float16><<<ggrid, 512, 0, stream>>>(xb, w1, b1, h1);
        gemm_bt<true, _Float16><<<ggrid, 512, 0, stream>>>(h1, w2, b2, h2);
        gemm_bt<false, float><<<ggrid, 512, 0, stream>>>(h2, w3, b3, out);
    } else {
        // 96MB fallback: shared per-layer W buffer
        _Float16* xb = (_Float16*)d_ws;
        _Float16* wb = (_Float16*)((char*)d_ws + HB);
        _Float16* h1 = (_Float16*)((char*)d_ws + HB * 2);
        _Float16* h2 = xb;

        cvt_f16_2<<<dim3(2048, 2), 256, 0, stream>>>(x, xb, W1, wb, n8);
        gemm_bt<true, _Float16><<<ggrid, 512, 0, stream>>>(xb, wb, b1, h1);
        cvt_f16<<<2048, 256, 0, stream>>>(W2, wb, n8);
        gemm_bt<true, _Float16><<<ggrid, 512, 0, stream>>>(h1, wb, b2, h2);
        cvt_f16<<<2048, 256, 0, stream>>>(W3, wb, n8);
        gemm_bt<false, float><<<ggrid, 512, 0, stream>>>(h2, wb, b3, out);
    }
}

// Round 5
// 577.922 us; speedup vs baseline: 1.1439x; 1.1439x over previous
//
#include <hip/hip_runtime.h>
#include <cstdint>

// SparseMLP: out = relu(relu(x@W1^T+b1)@W2^T+b2)@W3^T+b3
// M = N = K = 4096 per layer. fp32 in/out; fp16 MFMA internally.
//
// R9 vs R8 (661us, spill+staging regression) / R7 (589us, GEMM 121.6):
// BLOCKED GLOBAL LAYOUT so both staging and frag reads are linear.
//   f16 matrices stored as 16B chunks: g = (R*128 + T*2 + ks)*64 + kq*16 + r16
//   holding elems (row = R*16+r16, col = T*64 + ks*32 + kq*8 .. +8).
//   - glds16 source: contiguous 1KB per issue (1 VMEM segment).
//   - LDS region (16KB) = [fi 0..7][ks 0..1][1KB frag], frag = [kq][r16][16B]:
//     every ds_read_b128 is base + lane*16 (m134-optimal, no 2-way quarter
//     aliasing that R4-R7's XOR-chunk reads had; SQ_LDS_BANK_CONFLICT=0 was
//     necessary but not sufficient -- we sat at m198's 1167 TF exactly).
//   - reads spread 8/4/8/4 over 4 phases; per-phase in-phase reads + lgkm(0)
//     (m201 pattern). Frag regs: aP[4],bP[4],bQ[4] only.
//   - stages: P0={Ak0}, P1={Bk0}, P2={Ak1}, P3={Bk1} all for T+1 (dbuf);
//     vmcnt(4) at end-P1 (retires k1_T before P2 reads) and end-P3 (retires
//     k0_{T+1} before T+1 P0). Never 0 mid-loop; T=NT-1 end-P1 drains.
//   - GEMM1/2 epilogue writes h blocked directly (permutation only);
//     cvt_blk converts x,W1..W3 fp32->blocked f16 (1 launch roomy path).

#define MATN 4096
#define NT (MATN / 64)  // 64 K-tiles

typedef _Float16 half8 __attribute__((ext_vector_type(8)));
typedef float f32x4 __attribute__((ext_vector_type(4)));

// async global->LDS, 16B/lane. LDS dest = wave-uniform base + lane*16;
// global source is per-lane.
__device__ __forceinline__ void glds16(const void* g, void* l) {
    __builtin_amdgcn_global_load_lds(
        (const __attribute__((address_space(1))) char*)(uintptr_t)g,
        (__attribute__((address_space(3))) char*)(uintptr_t)l,
        16, 0, 0);
}

// fp32 row-major -> blocked f16. Per wave: 16 rows x 128B in-segments.
__device__ __forceinline__ void cvtblk_body(const float* __restrict__ in,
                                            _Float16* __restrict__ out, int n16) {
    for (int g = blockIdx.x * 256 + threadIdx.x; g < n16; g += gridDim.x * 256) {
        const int r16 = g & 15;
        const int kq  = (g >> 4) & 3;
        const int ks  = (g >> 6) & 1;
        const int T   = (g >> 7) & 63;
        const int R   = g >> 13;
        const size_t row = (size_t)R * 16 + r16;
        const int    col = T * 64 + ks * 32 + kq * 8;
        const float* p = in + row * MATN + col;
        float4 a = *(const float4*)p;
        float4 b = *(const float4*)(p + 4);
        half8 o;
        o[0] = (_Float16)a.x; o[1] = (_Float16)a.y;
        o[2] = (_Float16)a.z; o[3] = (_Float16)a.w;
        o[4] = (_Float16)b.x; o[5] = (_Float16)b.y;
        o[6] = (_Float16)b.z; o[7] = (_Float16)b.w;
        *(half8*)(out + (size_t)g * 8) = o;
    }
}

__global__ __launch_bounds__(256)
void cvt_blk(const float* __restrict__ in, _Float16* __restrict__ out, int n16) {
    cvtblk_body(in, out, n16);
}

__global__ __launch_bounds__(256)
void cvt_blk2(const float* __restrict__ i0, _Float16* __restrict__ o0,
              const float* __restrict__ i1, _Float16* __restrict__ o1, int n16) {
    cvtblk_body(blockIdx.y ? i1 : i0, blockIdx.y ? o1 : o0, n16);
}

__global__ __launch_bounds__(256)
void cvt_blk4(const float* __restrict__ i0, _Float16* __restrict__ o0,
              const float* __restrict__ i1, _Float16* __restrict__ o1,
              const float* __restrict__ i2, _Float16* __restrict__ o2,
              const float* __restrict__ i3, _Float16* __restrict__ o3, int n16) {
    const float* in;
    _Float16* out;
    switch (blockIdx.y) {
        case 0: in = i0; out = o0; break;
        case 1: in = i1; out = o1; break;
        case 2: in = i2; out = o2; break;
        default: in = i3; out = o3; break;
    }
    cvtblk_body(in, out, n16);
}

// C[m][n] = sum_k A[m][k]*B[n][k] + bias[n] (optional ReLU).
// A,B blocked-f16 (above). 256x256 tile, BK=64, 8 waves (2M x 4N),
// per-wave 128x64 out, acc[8][4]. OBLK: write C blocked-f16 (for h1/h2).
#define MFMA_(d, x, y) d = __builtin_amdgcn_mfma_f32_16x16x32_f16(x, y, d, 0, 0, 0)

template <bool RELU, bool OBLK, typename OutT>
__global__ __launch_bounds__(512, 2)
void gemm_blk(const _Float16* __restrict__ A, const _Float16* __restrict__ B,
              const float* __restrict__ bias, OutT* __restrict__ C) {
    // [buf 2][region 4][16KB]; regions: 0=Ah0 1=Bh0 2=Bh1 3=Ah1. 128 KB.
    // region = [fi 0..7][ks 0..1][1KB frag], frag read = base + lane*16.
    __shared__ _Float16 lds[2][4][128 * 64];

    const int tid  = threadIdx.x;
    const int lane = tid & 63;
    const int w    = tid >> 6;   // 8 waves
    const int wm   = w >> 2;     // 0..1: rows wm*128..+128
    const int wn   = w & 3;      // 0..3: cols wn*64..+64
    const int l16  = lane & 15;
    const int kq   = lane >> 4;

    // bijective XCD swizzle: 256 blocks, 256 % 8 == 0
    const int bid   = blockIdx.y * 16 + blockIdx.x;
    const int sbid  = (bid & 7) * 32 + (bid >> 3);
    const int tileM = (sbid >> 4) * 256;
    const int tileN = (sbid & 15) * 256;

    char* const ldsb = (char*)lds;

    // staging: unit (matrix-half h, ks j) = 8 waves x 1 glds16; wave w copies
    // global chunk-block (R = tilebase/16 + h*8 + w, T, ks=j) -> LDS frag
    // block (fi=w, ks=j). Source contiguous 1KB (per-lane +lane*16).
    const int lb = lane * 16;
    const char* const aSrc =
        (const char*)A + ((size_t)((tileM >> 4) + w) * 131072) + lb;
    const char* const bSrc =
        (const char*)B + ((size_t)((tileN >> 4) + w) * 131072) + lb;
    const int wj = w * 2048;

#define SA(Tt, h, j)                                                           \
    do {                                                                       \
        if ((Tt) < NT)                                                         \
            glds16(aSrc + (size_t)(h)*1048576 + (size_t)(Tt)*2048 + (j)*1024,  \
                   ldsb + ((Tt)&1) * 65536 + (h)*49152 + wj + (j)*1024);       \
    } while (0)
#define SB(Tt, h, j)                                                           \
    do {                                                                       \
        if ((Tt) < NT)                                                         \
            glds16(bSrc + (size_t)(h)*1048576 + (size_t)(Tt)*2048 + (j)*1024,  \
                   ldsb + ((Tt)&1) * 65536 + 16384 + (h)*16384 + wj +          \
                       (j)*1024);                                              \
    } while (0)

    half8 aP[4], bP[4], bQ[4];
    f32x4 acc[8][4] = {};

    // prologue: tile0's 8 units in order {Ak0,Bk0,Ak1,Bk1}; vmcnt(4)
    // retires the k0 units (what P0/P1 read), k1 stays in flight.
    SA(0, 0, 0); SA(0, 1, 0);
    SB(0, 0, 0); SB(0, 1, 0);
    SA(0, 0, 1); SA(0, 1, 1);
    SB(0, 0, 1); SB(0, 1, 1);
    asm volatile("s_waitcnt vmcnt(4)" ::: "memory");
    __builtin_amdgcn_s_barrier();

    for (int T = 0; T < NT; ++T) {
        const char* bufb = ldsb + (T & 1) * 65536;
        const char* Ard  = bufb + wm * 49152 + lb;  // region Ah_{wm}
        const char* Brd  = bufb + 16384 + (wn >> 1) * 16384 + (wn & 1) * 8192 + lb;

        // ---- P0: mi 0..3, ks0. reads aP (fi 0..3,k0) + bP (k0) = 8 ----
#pragma unroll
        for (int i = 0; i < 4; ++i) aP[i] = *(const half8*)(Ard + i * 2048);
#pragma unroll
        for (int n = 0; n < 4; ++n) bP[n] = *(const half8*)(Brd + n * 2048);
        SA(T + 1, 0, 0); SA(T + 1, 1, 0);  // Ak0_{T+1}
        __builtin_amdgcn_s_barrier();
        asm volatile("s_waitcnt lgkmcnt(0)" ::: "memory");
        __builtin_amdgcn_sched_barrier(0);
        __builtin_amdgcn_s_setprio(1);
#pragma unroll
        for (int i = 0; i < 4; ++i)
#pragma unroll
            for (int n = 0; n < 4; ++n) MFMA_(acc[i][n], aP[i], bP[n]);
        __builtin_amdgcn_s_setprio(0);
        __builtin_amdgcn_s_barrier();

        // ---- P1: mi 4..7, ks0. reads aP (fi 4..7,k0) = 4 ----
#pragma unroll
        for (int i = 0; i < 4; ++i)
            aP[i] = *(const half8*)(Ard + 8192 + i * 2048);
        SB(T + 1, 0, 0); SB(T + 1, 1, 0);  // Bk0_{T+1}
        __builtin_amdgcn_s_barrier();
        asm volatile("s_waitcnt lgkmcnt(0)" ::: "memory");
        __builtin_amdgcn_sched_barrier(0);
        __builtin_amdgcn_s_setprio(1);
#pragma unroll
        for (int i = 0; i < 4; ++i)
#pragma unroll
            for (int n = 0; n < 4; ++n) MFMA_(acc[4 + i][n], aP[i], bP[n]);
        __builtin_amdgcn_s_setprio(0);
        // retire k1_T (issued at T-1 P2/P3) before P2 reads it; keeps this
        // tile's 4 k0_{T+1} loads in flight. Tail tile has no new issues.
        if (T < NT - 1)
            asm volatile("s_waitcnt vmcnt(4)" ::: "memory");
        else
            asm volatile("s_waitcnt vmcnt(0)" ::: "memory");
        __builtin_amdgcn_s_barrier();

        // ---- P2: mi 4..7, ks1. reads aP (fi 4..7,k1) + bQ (k1) = 8 ----
#pragma unroll
        for (int i = 0; i < 4; ++i)
            aP[i] = *(const half8*)(Ard + 9216 + i * 2048);
#pragma unroll
        for (int n = 0; n < 4; ++n)
            bQ[n] = *(const half8*)(Brd + 1024 + n * 2048);
        SA(T + 1, 0, 1); SA(T + 1, 1, 1);  // Ak1_{T+1}
        __builtin_amdgcn_s_barrier();
        asm volatile("s_waitcnt lgkmcnt(0)" ::: "memory");
        __builtin_amdgcn_sched_barrier(0);
        __builtin_amdgcn_s_setprio(1);
#pragma unroll
        for (int i = 0; i < 4; ++i)
#pragma unroll
            for (int n = 0; n < 4; ++n) MFMA_(acc[4 + i][n], aP[i], bQ[n]);
        __builtin_amdgcn_s_setprio(0);
        __builtin_amdgcn_s_barrier();

        // ---- P3: mi 0..3, ks1. reads aP (fi 0..3,k1) = 4 ----
#pragma unroll
        for (int i = 0; i < 4; ++i)
            aP[i] = *(const half8*)(Ard + 1024 + i * 2048);
        SB(T + 1, 0, 1); SB(T + 1, 1, 1);  // Bk1_{T+1}
        __builtin_amdgcn_s_barrier();
        asm volatile("s_waitcnt lgkmcnt(0)" ::: "memory");
        __builtin_amdgcn_sched_barrier(0);
        __builtin_amdgcn_s_setprio(1);
#pragma unroll
        for (int i = 0; i < 4; ++i)
#pragma unroll
            for (int n = 0; n < 4; ++n) MFMA_(acc[i][n], aP[i], bQ[n]);
        __builtin_amdgcn_s_setprio(0);
        // retire k0_{T+1} (issued this tile P0/P1) before T+1's P0/P1 reads;
        // keeps k1_{T+1} (P2/P3's 4) in flight across the tile boundary.
        asm volatile("s_waitcnt vmcnt(4)" ::: "memory");
        __builtin_amdgcn_s_barrier();
    }
#undef SA
#undef SB

    // epilogue. acc[mi][ni] <-> rows tileM+wm*128+mi*16 (+kq*4+r),
    // cols tileN+wn*64+ni*16+l16. C/D layout col=lane&15, row=(lane>>4)*4+reg.
    if (OBLK) {
        // blocked store: byte = (R*128 + Tn*2 + ks)*1024 + kq'*256 + r16*16 + e*2
        char* const Cb = (char*)C;
        const int tN0 = tileN >> 6;
#pragma unroll
        for (int ni = 0; ni < 4; ++ni) {
            const int q  = ni * 16 + l16;  // col within wave's 64
            const float bv = bias[tileN + wn * 64 + q];
            const size_t colOff = (size_t)(((tN0 + wn) * 2 + ((q >> 5) & 1))) * 1024 +
                                  ((q >> 3) & 3) * 256 + (q & 7) * 2;
#pragma unroll
            for (int mi = 0; mi < 8; ++mi) {
                const size_t Roff =
                    (size_t)((tileM >> 4) + wm * 8 + mi) * 131072;
#pragma unroll
                for (int r = 0; r < 4; ++r) {
                    float v = acc[mi][ni][r] + bv;
                    if (RELU) v = v > 0.f ? v : 0.f;
                    *(_Float16*)(Cb + Roff + colOff + (kq * 4 + r) * 16) =
                        (_Float16)v;
                }
            }
        }
    } else {
#pragma unroll
        for (int ni = 0; ni < 4; ++ni) {
            const int gn = tileN + wn * 64 + ni * 16 + l16;
            const float bv = bias[gn];
#pragma unroll
            for (int mi = 0; mi < 8; ++mi) {
                const int gm = tileM + wm * 128 + mi * 16 + kq * 4;
#pragma unroll
                for (int r = 0; r < 4; ++r) {
                    float v = acc[mi][ni][r] + bv;
                    if (RELU) v = v > 0.f ? v : 0.f;
                    C[(size_t)(gm + r) * MATN + gn] = (OutT)v;
                }
            }
        }
    }
}

extern "C" void kernel_launch(void* const* d_in, const int* in_sizes, int n_in,
                              void* d_out, int out_size, void* d_ws, size_t ws_size,
                              hipStream_t stream) {
    const float* x  = (const float*)d_in[0];
    const float* W1 = (const float*)d_in[1];
    const float* b1 = (const float*)d_in[2];
    const float* W2 = (const float*)d_in[3];
    const float* b2 = (const float*)d_in[4];
    const float* W3 = (const float*)d_in[5];
    const float* b3 = (const float*)d_in[6];
    float* out = (float*)d_out;

    const size_t MAT = (size_t)MATN * MATN;
    const size_t HB  = MAT * 2;  // bytes per f16 matrix
    const int n16 = (int)(MAT / 8);
    dim3 ggrid(MATN / 256, MATN / 256);  // 16x16

    if (ws_size >= HB * 5) {
        _Float16* xb = (_Float16*)d_ws;
        _Float16* w1 = (_Float16*)((char*)d_ws + HB);
        _Float16* w2 = (_Float16*)((char*)d_ws + HB * 2);
        _Float16* w3 = (_Float16*)((char*)d_ws + HB * 3);
        _Float16* h1 = (_Float16*)((char*)d_ws + HB * 4);
        _Float16* h2 = xb;  // xb dead after layer 1

        cvt_blk4<<<dim3(8192, 4), 256, 0, stream>>>(x, xb, W1, w1, W2, w2,
                                                    W3, w3, n16);
        gemm_blk<true, true, _Float16><<<ggrid, 512, 0, stream>>>(xb, w1, b1, h1);
        gemm_blk<true, true, _Float16><<<ggrid, 512, 0, stream>>>(h1, w2, b2, h2);
        gemm_blk<false, false, float><<<ggrid, 512, 0, stream>>>(h2, w3, b3, out);
    } else {
        _Float16* xb = (_Float16*)d_ws;
        _Float16* wb = (_Float16*)((char*)d_ws + HB);
        _Float16* h1 = (_Float16*)((char*)d_ws + HB * 2);
        _Float16* h2 = xb;

        cvt_blk2<<<dim3(8192, 2), 256, 0, stream>>>(x, xb, W1, wb, n16);
        gemm_blk<true, true, _Float16><<<ggrid, 512, 0, stream>>>(xb, wb, b1, h1);
        cvt_blk<<<8192, 256, 0, stream>>>(W2, wb, n16);
        gemm_blk<true, true, _Float16><<<ggrid, 512, 0, stream>>>(h1, wb, b2, h2);
        cvt_blk<<<8192, 256, 0, stream>>>(W3, wb, n16);
        gemm_blk<false, false, float><<<ggrid, 512, 0, stream>>>(h2, wb, b3, out);
    }
}